// Round 5
// baseline (245.550 us; speedup 1.0000x reference)
//
#include <hip/hip_runtime.h>
#include <math.h>

#define C      256
#define NPIX   196
#define BATCH  64
#define MAT    65536                  // C*C
#define PL     4194304                // BATCH*MAT  (one bf16 plane, in elements)
#define OUTPB  32896                  // C*(C+1)/2

typedef short s16x8 __attribute__((ext_vector_type(8)));
typedef float f32x4 __attribute__((ext_vector_type(4)));

// ---- bf16 split helpers (RNE) ---------------------------------------------
__device__ __forceinline__ short bfhi(float v) {
    unsigned int u = __float_as_uint(v);
    u = (u + 0x7fffu + ((u >> 16) & 1u)) >> 16;
    return (short)u;
}
__device__ __forceinline__ float bff(short h) {
    return __uint_as_float(((unsigned int)(unsigned short)h) << 16);
}
__device__ __forceinline__ void bfsplit(float v, short& h, short& l) {
    h = bfhi(v);
    l = bfhi(v - bff(h));
}

// async 16B global -> LDS (linear dest, per-lane global src)
__device__ __forceinline__ void gload16(const short* g, short* l) {
    __builtin_amdgcn_global_load_lds((const __attribute__((address_space(1))) void*)g,
                                     (__attribute__((address_space(3))) void*)l, 16, 0, 0);
}

// ---------------------------------------------------------------------------
// convert: row-mean centering, bf16 hi/lo split, zero-pad K 196->256.
// ---------------------------------------------------------------------------
__global__ __launch_bounds__(256) void convert_k(const float* __restrict__ x,
                                                 short* __restrict__ xc,
                                                 float* __restrict__ rowsq) {
    const int bid = blockIdx.x;               // 4096 blocks
    const int xcd = bid & 7, j = bid >> 3;
    const int lb = j & 7, rc = j >> 3;
    const int b = xcd + (lb << 3);
    const int wave = threadIdx.x >> 6, lane = threadIdx.x & 63;
    const int row = rc * 4 + wave;
    const int rowg = b * 256 + row;
    const float* xr = x + (size_t)rowg * NPIX;
    float v[4];
    #pragma unroll
    for (int i = 0; i < 4; ++i) {
        int c = lane + (i << 6);
        v[i] = (c < NPIX) ? xr[c] : 0.f;
    }
    float s = v[0] + v[1] + v[2] + v[3];
    #pragma unroll
    for (int off = 32; off; off >>= 1) s += __shfl_xor(s, off, 64);
    const float mean = s * (1.f / NPIX);

    short* oh = xc + (size_t)b * MAT + (size_t)row * C;
    short* ol = oh + PL;
    float sq = 0.f;
    #pragma unroll
    for (int i = 0; i < 4; ++i) {
        int c = lane + (i << 6);
        float w = (c < NPIX) ? (v[i] - mean) : 0.f;
        sq += w * w;
        short h, l;
        bfsplit(w, h, l);
        oh[c] = h;
        ol[c] = l;
    }
    #pragma unroll
    for (int off = 32; off; off >>= 1) sq += __shfl_xor(sq, off, 64);
    if (lane == 0) rowsq[rowg] = sq;
}

// ---------------------------------------------------------------------------
__global__ __launch_bounds__(256) void tracered_k(const float* __restrict__ rowsq,
                                                  float* __restrict__ trsum) {
    const int b = blockIdx.x, t = threadIdx.x;
    float v = rowsq[b * 256 + t];
    __shared__ float red[4];
    #pragma unroll
    for (int off = 32; off; off >>= 1) v += __shfl_xor(v, off, 64);
    if ((t & 63) == 0) red[t >> 6] = v;
    __syncthreads();
    if (t == 0) trsum[b] = red[0] + red[1] + red[2] + red[3];
}

// ---------------------------------------------------------------------------
// Batched split-bf16 MFMA matmul, tile BM=64 x BN=128, HALF-BATCH (32 b).
// Grid: singles 256 blocks (1/CU), pair (MODE 4) 512. XCD-pinned b = bbase+xcd+8q.
// Staging: global_load_lds 16B, pre-swizzled per-lane global addr, LDS linear,
// double-buffered, counted vmcnt(12) + raw s_barrier (loads in flight across
// barriers; __syncthreads would drain vmcnt(0)).
// MODE 0: o0 = A@B        MODE 1: o0 = 1.5I - 0.5 A@B
// MODE 2: outf = triu_packed(A@B * sqrt(tr/n))
// MODE 3: (gram) o0 = P/trsum ; o1 = 1.5I - 0.5*o0
// MODE 4: pair — half 0: o0 = A0@B ; half 1: o1 = A1@B
// ---------------------------------------------------------------------------
template <int MODE>
__global__ __launch_bounds__(256) void mm_k(const short* __restrict__ A0,
                                            const short* __restrict__ A1,
                                            const short* __restrict__ Bop,
                                            short* __restrict__ o0,
                                            short* __restrict__ o1,
                                            float* __restrict__ outf,
                                            const float* __restrict__ trsum,
                                            int bbase) {
    const int bid = blockIdx.x;
    const int xcd = bid & 7, j = bid >> 3;
    const int t8 = j & 7;
    const int bm = t8 >> 1, bn = t8 & 1;
    const int q = j >> 3;
    const int half = (MODE == 4) ? (q >> 2) : 0;
    const int b = bbase + xcd + (((MODE == 4) ? (q & 3) : q) << 3);
    if (MODE == 2 && bn == 0 && bm >= 2) return;

    __shared__ __align__(16) short lds[2 * 24576];   // 96 KB double buffer

    const int t = threadIdx.x;
    const int lane = t & 63, wid = t >> 6;
    const int wr = wid >> 1, wc = wid & 1;
    const int lr = lane & 15, lg = lane >> 4;

    const size_t mb = (size_t)b * MAT;
    const short* Ap = ((MODE == 4 && half) ? A1 : A0) + mb;
    const short* Bp = Bop + mb;
    const int rowA0 = bm * 64, rowB0 = bn * 128;

    // 12 per-lane pre-swizzled global srcs; LDS dest stays linear.
    // slots: i 0-1 A-hi, 2-3 A-lo, 4-7 B-hi, 8-11 B-lo
    const short* gp[12];
    #pragma unroll
    for (int i = 0; i < 12; ++i) {
        int rr;
        const short* pp;
        if (i < 4) {
            rr = (i & 1) * 32 + (t >> 3);
            pp = Ap + (size_t)(i >> 1) * PL + (size_t)(rowA0 + rr) * C;
        } else {
            rr = ((i - 4) & 3) * 32 + (t >> 3);
            pp = Bp + (size_t)((i - 4) >> 2) * PL + (size_t)(rowB0 + rr) * C;
        }
        gp[i] = pp + (((t & 7) ^ (rr & 7)) << 3);
    }

    f32x4 acc[2][4];
    const f32x4 zero = {0.f, 0.f, 0.f, 0.f};
    #pragma unroll
    for (int i = 0; i < 2; ++i)
        #pragma unroll
        for (int jj = 0; jj < 4; ++jj) acc[i][jj] = zero;

    // prologue: stage k0=0 into buffer 0
    #pragma unroll
    for (int i = 0; i < 12; ++i)
        gload16(gp[i], lds + i * 2048 + wid * 512);

    for (int ks = 0; ks < 4; ++ks) {
        const int cur = ks & 1;
        if (ks < 3) {
            const int nxt = cur ^ 1;
            #pragma unroll
            for (int i = 0; i < 12; ++i)
                gload16(gp[i] + (ks + 1) * 64, lds + nxt * 24576 + i * 2048 + wid * 512);
            asm volatile("s_waitcnt vmcnt(12)" ::: "memory");   // cur buffer landed
        } else {
            asm volatile("s_waitcnt vmcnt(0)" ::: "memory");
        }
        __builtin_amdgcn_s_barrier();
        __builtin_amdgcn_sched_barrier(0);
        const short* L = lds + cur * 24576;
        #pragma unroll
        for (int kk = 0; kk < 64; kk += 32) {
            s16x8 ah[2], al[2], bh[4], bl[4];
            #pragma unroll
            for (int i = 0; i < 2; ++i) {
                const int ra = wr * 32 + i * 16 + lr;
                const int ca = ((kk >> 3) + lg) ^ (ra & 7);
                ah[i] = *(const s16x8*)&L[ra * 64 + (ca << 3)];
                al[i] = *(const s16x8*)&L[4096 + ra * 64 + (ca << 3)];
            }
            #pragma unroll
            for (int jj = 0; jj < 4; ++jj) {
                const int rb = wc * 64 + jj * 16 + lr;
                const int cb = ((kk >> 3) + lg) ^ (rb & 7);
                bh[jj] = *(const s16x8*)&L[8192 + rb * 64 + (cb << 3)];
                bl[jj] = *(const s16x8*)&L[16384 + rb * 64 + (cb << 3)];
            }
            #pragma unroll
            for (int i = 0; i < 2; ++i)
                #pragma unroll
                for (int jj = 0; jj < 4; ++jj) {
                    acc[i][jj] = __builtin_amdgcn_mfma_f32_16x16x32_bf16(ah[i], bh[jj], acc[i][jj], 0, 0, 0);
                    acc[i][jj] = __builtin_amdgcn_mfma_f32_16x16x32_bf16(ah[i], bl[jj], acc[i][jj], 0, 0, 0);
                    acc[i][jj] = __builtin_amdgcn_mfma_f32_16x16x32_bf16(al[i], bh[jj], acc[i][jj], 0, 0, 0);
                }
        }
        __builtin_amdgcn_sched_barrier(0);
        __builtin_amdgcn_s_barrier();
    }

    // ---- epilogue ----
    float ts = 0.f;
    if (MODE == 2 || MODE == 3) ts = trsum[b];
    const float invT  = (MODE == 3) ? (1.f / ts) : 0.f;
    const float scale = (MODE == 2) ? sqrtf(ts * (1.f / NPIX)) : 0.f;
    short* dst = (MODE == 4 && half) ? o1 : o0;

    #pragma unroll
    for (int i = 0; i < 2; ++i) {
        #pragma unroll
        for (int jj = 0; jj < 4; ++jj) {
            #pragma unroll
            for (int qq = 0; qq < 4; ++qq) {
                const int r_t = bm * 64 + wr * 32 + i * 16 + lg * 4 + qq;
                const int c_t = bn * 128 + wc * 64 + jj * 16 + lr;
                const float v = acc[i][jj][qq];
                if (MODE == 0 || MODE == 4) {
                    short h, l;
                    bfsplit(v, h, l);
                    dst[mb + (size_t)r_t * C + c_t] = h;
                    dst[(size_t)PL + mb + (size_t)r_t * C + c_t] = l;
                } else if (MODE == 1) {
                    float w = ((r_t == c_t) ? 1.5f : 0.f) - 0.5f * v;
                    short h, l;
                    bfsplit(w, h, l);
                    o0[mb + (size_t)r_t * C + c_t] = h;
                    o0[(size_t)PL + mb + (size_t)r_t * C + c_t] = l;
                } else if (MODE == 3) {
                    float a = v * invT;
                    short h, l;
                    bfsplit(a, h, l);
                    o0[mb + (size_t)r_t * C + c_t] = h;
                    o0[(size_t)PL + mb + (size_t)r_t * C + c_t] = l;
                    float w = ((r_t == c_t) ? 1.5f : 0.f) - 0.5f * a;
                    bfsplit(w, h, l);
                    o1[mb + (size_t)r_t * C + c_t] = h;
                    o1[(size_t)PL + mb + (size_t)r_t * C + c_t] = l;
                } else if (MODE == 2) {
                    if (c_t >= r_t) {
                        int off = r_t * C - (r_t * (r_t - 1)) / 2 - r_t + c_t;
                        outf[(size_t)b * OUTPB + off] = v * scale;
                    }
                }
            }
        }
    }
}

// ---------------------------------------------------------------------------
extern "C" void kernel_launch(void* const* d_in, const int* in_sizes, int n_in,
                              void* d_out, int out_size, void* d_ws, size_t ws_size,
                              hipStream_t stream) {
    const float* x = (const float*)d_in[0];
    float* out = (float*)d_out;
    short* base = (short*)d_ws;
    short* b0 = base;
    short* b1 = base + (size_t)2 * PL;
    short* b2 = base + (size_t)4 * PL;
    short* b3 = base + (size_t)6 * PL;
    short* b4 = base + (size_t)8 * PL;   // doubles as xc
    float* trsum = (float*)(base + (size_t)10 * PL);
    float* rowsq = trsum + 256;

    dim3 blk(256);

    // xc (centered, split, padded) -> b4 ; rowsq ; trsum
    convert_k<<<dim3(4096), blk, 0, stream>>>(x, b4, rowsq);
    tracered_k<<<dim3(64), blk, 0, stream>>>(rowsq, trsum);

    // Newton-Schulz chain, half-batch at a time (L2-resident per XCD)
    for (int h = 0; h < 2; ++h) {
        const int bb = h * 32;
        dim3 gS(256), gP(512);
        // gram: A -> b0, Z1 -> b1
        mm_k<3><<<gS, blk, 0, stream>>>(b4, b4, b4, b0, b1, nullptr, trsum, bb);
        // Y1 = A @ Z1 -> b2
        mm_k<0><<<gS, blk, 0, stream>>>(b0, b0, b1, b2, nullptr, nullptr, nullptr, bb);
        // iter 1
        mm_k<1><<<gS, blk, 0, stream>>>(b1, b1, b2, b3, nullptr, nullptr, nullptr, bb); // Bn1=b3
        mm_k<4><<<gP, blk, 0, stream>>>(b2, b1, b3, b0, b4, nullptr, nullptr, bb);      // Y->b0, Z->b4
        // iter 2
        mm_k<1><<<gS, blk, 0, stream>>>(b4, b4, b0, b1, nullptr, nullptr, nullptr, bb); // Bn2=b1
        mm_k<4><<<gP, blk, 0, stream>>>(b0, b4, b1, b2, b3, nullptr, nullptr, bb);      // Y->b2, Z->b3
        // iter 3
        mm_k<1><<<gS, blk, 0, stream>>>(b3, b3, b2, b0, nullptr, nullptr, nullptr, bb); // Bn3=b0
        mm_k<4><<<gP, blk, 0, stream>>>(b2, b3, b0, b4, b1, nullptr, nullptr, bb);      // Y->b4, Z->b1
        // final
        mm_k<1><<<gS, blk, 0, stream>>>(b1, b1, b4, b2, nullptr, nullptr, nullptr, bb); // Bf=b2
        mm_k<2><<<gS, blk, 0, stream>>>(b4, b4, b2, nullptr, nullptr, out, trsum, bb);  // out
    }
}